// Round 28
// baseline (392.051 us; speedup 1.0000x reference)
//
#include <hip/hip_runtime.h>
#include <hip/hip_bf16.h>
#include <math.h>

#define NB 256
#define NL 50
#define NK 100
#define NHID 64
#define NBL (NB * NL)            // 12800 (b,l) pairs
#define EGRID 1024               // persistent-ish edge grid (4 blocks/CU)

typedef __attribute__((ext_vector_type(8))) short short8;   // 8 bf16 = 4 VGPR
typedef __attribute__((ext_vector_type(4))) short short4_t; // 4 bf16 = 8B
typedef __attribute__((ext_vector_type(4))) float floatx4;  // C/D frag

#define ZSTRIDE 208              // 16x13 dwords: 16B-aligned, bank-shift 20/row

__device__ __forceinline__ short f2bf(float f) {
    __hip_bfloat16 h = __float2bfloat16(f);
    return *reinterpret_cast<short*>(&h);
}

// ---- pack weights (bf16 k-major frags); gridified (R24-proven) ----
__global__ __launch_bounds__(256) void pack_kernel(
    const float* __restrict__ Wa, const float* __restrict__ W1,
    const float* __restrict__ W2,
    short* __restrict__ WaP, short* __restrict__ W1P, short* __restrict__ W2P)
{
    int t = blockIdx.x * 256 + threadIdx.x;
    int stride = gridDim.x * 256;
    for (int s = t; s < 24 * 64; s += stride) {     // Wa full [128,96]: 6 ntiles x 4 ksteps
        int l = s & 63, fi = s >> 6, n = fi >> 2, tk = fi & 3;
        int col = n * 16 + (l & 15);
        for (int j = 0; j < 8; ++j) {
            int k = tk * 32 + ((l >> 4) * 8) + j;
            WaP[s * 8 + j] = f2bf(Wa[k * 96 + col]);
        }
    }
    for (int s = t; s < 9 * 64; s += stride) {      // W1 [96,48]: 3 ntiles x 3 ksteps
        int l = s & 63, nt = s >> 6, n = nt / 3, tk = nt % 3;
        int col = n * 16 + (l & 15);
        for (int j = 0; j < 8; ++j) {
            int k = tk * 32 + ((l >> 4) * 8) + j;
            W1P[s * 8 + j] = f2bf(W1[k * 48 + col]);
        }
    }
    for (int s = t; s < 2 * 64; s += stride) {      // W2 [48,16] pad K->64
        int l = s & 63, tk = s >> 6;
        int col = l & 15;
        for (int j = 0; j < 8; ++j) {
            int k = tk * 32 + ((l >> 4) * 8) + j;
            W2P[s * 8 + j] = (k < 48) ? f2bf(W2[k * 16 + col]) : (short)0;
        }
    }
}

// ---- fused edge kernel: persistent-ish, grid-stride over (b,l) ----
// R25/R27 proven body + cross-iteration prefetch: next bl's 12 float4
// (hist + tileA + tileB rows) are issued right after the current frags are
// converted, hiding the dependent history->item_table->row chain under the
// ~9K-cycle MLP+softmax+agg of the current iteration. 1024 blocks amortize
// 12800 workgroup dispatch+cold-start overheads.
__global__ __launch_bounds__(256) void edge_kernel(
    const int* __restrict__ history,
    const float* __restrict__ neighbor,
    const float* __restrict__ item_table,
    const float* __restrict__ b1v, const float* __restrict__ b2,
    const float* __restrict__ W3, const float* __restrict__ b3,
    const short* __restrict__ WaP, const short* __restrict__ W1P,
    const short* __restrict__ W2P,
    float* __restrict__ part)        // [NBL*4][64] per-(bl,wave) partials
{
    const int tid = threadIdx.x;
    const int wv  = tid >> 6;        // 0..3
    const int ln  = tid & 63;
    const int lr  = ln & 15;         // edge within tile (C-col after swap)
    const int lg  = ln >> 4;         // feat-group (C-row-group)

    __shared__ __align__(16) char z_s[7][16 * ZSTRIDE];  // scratch per TILE (mi 0..6)
    __shared__ float logit_s[112];
    const int mi1 = wv + 4;                              // tile B index (wv<3 only)
    const bool hasB = (mi1 < 7);
    char* zpA = z_s[wv];
    char* zpB = z_s[hasB ? mi1 : wv];                    // guarded

    const short8* WaPv = reinterpret_cast<const short8*>(WaP);
    const short8* W1Pv = reinterpret_cast<const short8*>(W1P);
    const short8* W2Pv = reinterpret_cast<const short8*>(W2P);
    const float b3s = b3[0];
    const floatx4 b2v = *reinterpret_cast<const floatx4*>(b2 + lg * 4);
    const floatx4 w3v = *reinterpret_cast<const floatx4*>(W3 + lg * 4);

    // per-bl row offsets (bl-independent parts)
    const int er0 = wv * 16 + lr;                        // tile A edge (<100)
    const int er1 = mi1 * 16 + lr;
    const int ec1 = (er1 > NK - 1) ? NK - 1 : er1;       // clamp junk rows

    // ---- prefetch loader: 12 float4 = hist(4) + tileA(4) + tileB(4) ----
    auto load_bl = [&](int bl, float4* buf) {
        const float* hb = item_table + (size_t)history[bl] * NHID;
        buf[0] = *reinterpret_cast<const float4*>(hb + lg * 8);
        buf[1] = *reinterpret_cast<const float4*>(hb + lg * 8 + 4);
        buf[2] = *reinterpret_cast<const float4*>(hb + 32 + lg * 8);
        buf[3] = *reinterpret_cast<const float4*>(hb + 32 + lg * 8 + 4);
        const float* nb = neighbor + (size_t)bl * (NK * NHID);
        const float* rA = nb + er0 * NHID + lg * 8;
        buf[4] = *reinterpret_cast<const float4*>(rA);
        buf[5] = *reinterpret_cast<const float4*>(rA + 4);
        buf[6] = *reinterpret_cast<const float4*>(rA + 32);
        buf[7] = *reinterpret_cast<const float4*>(rA + 36);
        const float* rB = nb + ec1 * NHID + lg * 8;
        buf[8]  = *reinterpret_cast<const float4*>(rB);
        buf[9]  = *reinterpret_cast<const float4*>(rB + 4);
        buf[10] = *reinterpret_cast<const float4*>(rB + 32);
        buf[11] = *reinterpret_cast<const float4*>(rB + 36);
    };
    auto cvt8 = [](float4 x, float4 y) {
        short8 r;
        r[0] = f2bf(x.x); r[1] = f2bf(x.y); r[2] = f2bf(x.z); r[3] = f2bf(x.w);
        r[4] = f2bf(y.x); r[5] = f2bf(y.y); r[6] = f2bf(y.z); r[7] = f2bf(y.w);
        return r;
    };

    // ---- stage lambdas (R22-proven math) ----
    auto l1_stage = [&](char* zp, short8 h0, short8 h1, short8 b0, short8 b1) {
        #pragma unroll
        for (int t = 0; t < 6; ++t) {
            floatx4 acc = {0.f, 0.f, 0.f, 0.f};
            acc = __builtin_amdgcn_mfma_f32_16x16x32_bf16(WaPv[(t * 4 + 0) * 64 + ln], h0, acc, 0, 0, 0);
            acc = __builtin_amdgcn_mfma_f32_16x16x32_bf16(WaPv[(t * 4 + 1) * 64 + ln], h1, acc, 0, 0, 0);
            acc = __builtin_amdgcn_mfma_f32_16x16x32_bf16(WaPv[(t * 4 + 2) * 64 + ln], b0, acc, 0, 0, 0);
            acc = __builtin_amdgcn_mfma_f32_16x16x32_bf16(WaPv[(t * 4 + 3) * 64 + ln], b1, acc, 0, 0, 0);
            short4_t v;
            #pragma unroll
            for (int i = 0; i < 4; ++i) v[i] = f2bf(fmaxf(acc[i], 0.f));
            *reinterpret_cast<short4_t*>(zp + lr * ZSTRIDE + t * 32 + lg * 8) = v;
        }
    };
    auto l2_stage = [&](char* zp) {
        short8 za0 = *reinterpret_cast<const short8*>(zp + lr * ZSTRIDE +   0 + lg * 16);
        short8 za1 = *reinterpret_cast<const short8*>(zp + lr * ZSTRIDE +  64 + lg * 16);
        short8 za2 = *reinterpret_cast<const short8*>(zp + lr * ZSTRIDE + 128 + lg * 16);
        #pragma unroll
        for (int t = 0; t < 3; ++t) {
            floatx4 acc = {0.f, 0.f, 0.f, 0.f};
            acc = __builtin_amdgcn_mfma_f32_16x16x32_bf16(W1Pv[(t * 3 + 0) * 64 + ln], za0, acc, 0, 0, 0);
            acc = __builtin_amdgcn_mfma_f32_16x16x32_bf16(W1Pv[(t * 3 + 1) * 64 + ln], za1, acc, 0, 0, 0);
            acc = __builtin_amdgcn_mfma_f32_16x16x32_bf16(W1Pv[(t * 3 + 2) * 64 + ln], za2, acc, 0, 0, 0);
            floatx4 bb = *reinterpret_cast<const floatx4*>(b1v + t * 16 + lg * 4);
            short4_t v;
            #pragma unroll
            for (int i = 0; i < 4; ++i) v[i] = f2bf(fmaxf(acc[i] + bb[i], 0.f));
            *reinterpret_cast<short4_t*>(zp + lr * ZSTRIDE + t * 32 + lg * 8) = v;
        }
    };
    auto l3_stage = [&](char* zp, int mi) {
        short8 zb0 = *reinterpret_cast<const short8*>(zp + lr * ZSTRIDE + lg * 16);
        short8 zb1 = short8{0, 0, 0, 0, 0, 0, 0, 0};
        if (lg < 2)
            zb1 = *reinterpret_cast<const short8*>(zp + lr * ZSTRIDE + 64 + lg * 16);
        floatx4 c3 = {0.f, 0.f, 0.f, 0.f};
        c3 = __builtin_amdgcn_mfma_f32_16x16x32_bf16(W2Pv[ln], zb0, c3, 0, 0, 0);
        c3 = __builtin_amdgcn_mfma_f32_16x16x32_bf16(W2Pv[64 + ln], zb1, c3, 0, 0, 0);
        float p = 0.f;
        #pragma unroll
        for (int i = 0; i < 4; ++i)
            p += fmaxf(c3[i] + b2v[i], 0.f) * w3v[i];
        p += __shfl_xor(p, 16, 64);
        p += __shfl_xor(p, 32, 64);
        if (lg == 0 && mi * 16 + lr < NK) logit_s[mi * 16 + lr] = p + b3s;
    };

    // ---- prologue: prefetch first bl ----
    float4 cur[12], nxt[12];
    if (blockIdx.x < NBL) load_bl(blockIdx.x, cur);

    for (int bl = blockIdx.x; bl < NBL; bl += EGRID) {
        // convert prefetched regs -> frags
        short8 h0 = cvt8(cur[0], cur[1]),  h1 = cvt8(cur[2], cur[3]);
        short8 a0 = cvt8(cur[4], cur[5]),  a1 = cvt8(cur[6], cur[7]);
        short8 a2 = cvt8(cur[8], cur[9]),  a3 = cvt8(cur[10], cur[11]);

        // issue NEXT bl's loads (9K-cycle shadow to complete)
        const int nbl = bl + EGRID;
        if (nbl < NBL) load_bl(nbl, nxt);

        // ---- interleaved MLP (A/B streams independent) ----
        l1_stage(zpA, h0, h1, a0, a1);
        if (hasB) l1_stage(zpB, h0, h1, a2, a3);
        l2_stage(zpA);
        if (hasB) l2_stage(zpB);
        l3_stage(zpA, wv);
        if (hasB) l3_stage(zpB, mi1);
        __syncthreads();                              // logits ready

        // ---- softmax (redundant per wave, in-register) ----
        float l0 = logit_s[ln];
        float l1 = (ln < NK - 64) ? logit_s[64 + ln] : -1e30f;
        __syncthreads();                              // logit_s dead -> next iter may write
        float m = fmaxf(l0, l1);
        #pragma unroll
        for (int off = 32; off > 0; off >>= 1) m = fmaxf(m, __shfl_xor(m, off, 64));
        float p0 = __expf(l0 - m);
        float p1 = (ln < NK - 64) ? __expf(l1 - m) : 0.f;
        float s = p0 + p1;
        #pragma unroll
        for (int off = 32; off > 0; off >>= 1) s += __shfl_xor(s, off, 64);
        float inv = 1.f / s;
        float w0 = p0 * inv;
        float w1 = p1 * inv;

        // ---- partial agg over this wave's 25 edges (L2-hot rows) ----
        const float* nbg = neighbor + (size_t)bl * (NK * NHID);
        float a = 0.f;
        #pragma unroll
        for (int kk = 0; kk < 25; ++kk) {
            int k = wv * 25 + kk;
            float wk = __shfl((k < 64) ? w0 : w1, k & 63, 64);
            a += wk * nbg[k * NHID + ln];
        }
        part[((size_t)bl * 4 + wv) * NHID + ln] = a;

        // rotate prefetch buffer (static full unroll)
        #pragma unroll
        for (int i = 0; i < 12; ++i) cur[i] = nxt[i];
    }
}

// ---- final head: reduce partials (256 thr, 4-way) -> heads -> Wf1 -> Wo ----
__global__ __launch_bounds__(256) void final_kernel(
    const int* __restrict__ user_ids,
    const float* __restrict__ user_table,
    const float* __restrict__ part,
    const float* __restrict__ Wh, const float* __restrict__ bh,
    const float* __restrict__ Wf1, const float* __restrict__ bf1,
    const float* __restrict__ Wo,  const float* __restrict__ bo,
    float* __restrict__ out)
{
    const int b = blockIdx.x, tid = threadIdx.x;
    const int q = tid >> 6, h = tid & 63;
    __shared__ float red[4][64];
    __shared__ float ue[64], agm[64], agh[64];

    {
        float sum = 0.f;
        const float* pb = part + ((size_t)b * NL * 4 + q) * NHID + h;
        #pragma unroll 5
        for (int i = 0; i < NL; ++i)
            sum += pb[(size_t)i * 4 * NHID];
        red[q][h] = sum;
    }
    if (q == 0) {
        const int uid = user_ids[b];
        ue[h] = user_table[(size_t)uid * 64 + h];
    }
    __syncthreads();
    if (q == 0)
        agm[h] = (red[0][h] + red[1][h] + red[2][h] + red[3][h]) * (1.f / 50.f);
    __syncthreads();
    if (q == 0) {
        const int n = h >> 4, d = h & 15;
        float hv = bh[h];
        #pragma unroll 4
        for (int i = 0; i < 64; ++i)
            hv += agm[i] * Wh[n * (64 * 16) + i * 16 + d];
        agh[h] = hv;
    }
    __syncthreads();
    if (q == 0) {
        float z = bf1[h];
        #pragma unroll 4
        for (int i = 0; i < 64; ++i) z += ue[i] * Wf1[i * 64 + h];
        #pragma unroll 4
        for (int i = 0; i < 64; ++i) z += agh[i] * Wf1[(64 + i) * 64 + h];
        float t = fmaxf(z, 0.f) * Wo[h];
        #pragma unroll
        for (int off = 32; off > 0; off >>= 1) t += __shfl_down(t, off, 64);
        if (h == 0) out[b] = 1.f / (1.f + __expf(-(t + bo[0])));
    }
}

extern "C" void kernel_launch(void* const* d_in, const int* in_sizes, int n_in,
                              void* d_out, int out_size, void* d_ws, size_t ws_size,
                              hipStream_t stream) {
    const int*   user_ids   = (const int*)d_in[0];
    const int*   history    = (const int*)d_in[2];
    const float* neighbor   = (const float*)d_in[3];
    const float* user_table = (const float*)d_in[4];
    const float* item_table = (const float*)d_in[5];
    const float* Wa  = (const float*)d_in[6];
    const float* W1  = (const float*)d_in[8];
    const float* b1  = (const float*)d_in[9];
    const float* W2  = (const float*)d_in[10];
    const float* b2  = (const float*)d_in[11];
    const float* W3  = (const float*)d_in[12];
    const float* b3  = (const float*)d_in[13];
    const float* Wh  = (const float*)d_in[14];
    const float* bh  = (const float*)d_in[15];
    const float* Wf1 = (const float*)d_in[16];
    const float* bf1 = (const float*)d_in[17];
    const float* Wo  = (const float*)d_in[18];
    const float* bo  = (const float*)d_in[19];

    char* ws = (char*)d_ws;
    short* WaP  = (short*)(ws);                              // 24576 B (full Wa)
    short* W1P  = (short*)(ws + 24576);                      // 9216 B
    short* W2P  = (short*)(ws + 33792);                      // 2048 B
    float* part = (float*)(ws + 36864);                      // NBL*4*64*4 = 13107200 B

    pack_kernel<<<64, 256, 0, stream>>>(Wa, W1, W2, WaP, W1P, W2P);
    edge_kernel<<<EGRID, 256, 0, stream>>>(history, neighbor, item_table,
        b1, b2, W3, b3, WaP, W1P, W2P, part);
    final_kernel<<<NB, 256, 0, stream>>>(user_ids, user_table, part, Wh, bh,
                                         Wf1, bf1, Wo, bo, (float*)d_out);
}

// Round 29
// 196.517 us; speedup vs baseline: 1.9950x; 1.9950x over previous
//
#include <hip/hip_runtime.h>
#include <hip/hip_bf16.h>
#include <math.h>

#define NB 256
#define NL 50
#define NK 100
#define NHID 64
#define NBL (NB * NL)            // 12800 (b,l) pairs

typedef __attribute__((ext_vector_type(8))) short short8;   // 8 bf16 = 4 VGPR
typedef __attribute__((ext_vector_type(4))) short short4_t; // 4 bf16 = 8B
typedef __attribute__((ext_vector_type(4))) float floatx4;  // C/D frag

#define ZSTRIDE 208              // 16x13 dwords: 16B-aligned, bank-shift 20/row

__device__ __forceinline__ short f2bf(float f) {
    __hip_bfloat16 h = __float2bfloat16(f);
    return *reinterpret_cast<short*>(&h);
}

// ---- pack weights (bf16 k-major frags); gridified (R24-proven) ----
__global__ __launch_bounds__(256) void pack_kernel(
    const float* __restrict__ Wa, const float* __restrict__ W1,
    const float* __restrict__ W2,
    short* __restrict__ WaP, short* __restrict__ W1P, short* __restrict__ W2P)
{
    int t = blockIdx.x * 256 + threadIdx.x;
    int stride = gridDim.x * 256;
    for (int s = t; s < 24 * 64; s += stride) {     // Wa full [128,96]: 6 ntiles x 4 ksteps
        int l = s & 63, fi = s >> 6, n = fi >> 2, tk = fi & 3;
        int col = n * 16 + (l & 15);
        for (int j = 0; j < 8; ++j) {
            int k = tk * 32 + ((l >> 4) * 8) + j;
            WaP[s * 8 + j] = f2bf(Wa[k * 96 + col]);
        }
    }
    for (int s = t; s < 9 * 64; s += stride) {      // W1 [96,48]: 3 ntiles x 3 ksteps
        int l = s & 63, nt = s >> 6, n = nt / 3, tk = nt % 3;
        int col = n * 16 + (l & 15);
        for (int j = 0; j < 8; ++j) {
            int k = tk * 32 + ((l >> 4) * 8) + j;
            W1P[s * 8 + j] = f2bf(W1[k * 48 + col]);
        }
    }
    for (int s = t; s < 2 * 64; s += stride) {      // W2 [48,16] pad K->64
        int l = s & 63, tk = s >> 6;
        int col = l & 15;
        for (int j = 0; j < 8; ++j) {
            int k = tk * 32 + ((l >> 4) * 8) + j;
            W2P[s * 8 + j] = (k < 48) ? f2bf(W2[k * 16 + col]) : (short)0;
        }
    }
}

// ---- fused edge kernel: one block per (b,l), 4 waves x 2 M-tiles ----
// R27 MEASURED-BEST (197.2us total, 4.1x over baseline). K=128 hist-fold,
// swapped MFMA + b64 z-writes (pad-208 rows), tile-phase ILP interleave via
// separate LDS scratch, 1 barrier, contention-free partial stores.
// Falsified levers (do NOT retry): VGPR caps (R19), extra live frags (R23),
// persistent prefetch (R28: VGPR 212, occ 12%), shfl-regroup (R17).
__global__ __launch_bounds__(256) void edge_kernel(
    const int* __restrict__ history,
    const float* __restrict__ neighbor,
    const float* __restrict__ item_table,
    const float* __restrict__ b1v, const float* __restrict__ b2,
    const float* __restrict__ W3, const float* __restrict__ b3,
    const short* __restrict__ WaP, const short* __restrict__ W1P,
    const short* __restrict__ W2P,
    float* __restrict__ part)        // [NBL*4][64] per-(bl,wave) partials
{
    const int bl  = blockIdx.x;
    const int tid = threadIdx.x;
    const int wv  = tid >> 6;        // 0..3
    const int ln  = tid & 63;
    const int lr  = ln & 15;         // edge within tile (C-col after swap)
    const int lg  = ln >> 4;         // feat-group (C-row-group)

    __shared__ __align__(16) char z_s[7][16 * ZSTRIDE];  // scratch per TILE (mi 0..6)
    __shared__ float logit_s[112];
    const int mi1 = wv + 4;                              // tile B index (wv<3 only)
    const bool hasB = (mi1 < 7);
    char* zpA = z_s[wv];                                 // tile A = wv
    char* zpB = z_s[hasB ? mi1 : wv];                    // guarded (never used if !hasB)

    const float* nbg = neighbor + (size_t)bl * (NK * NHID);

    // ---- hist fragments (k=0..63 of concat; edge-invariant broadcast) ----
    const int hid = history[bl];
    const float* hbase = item_table + (size_t)hid * NHID;
    short8 h0, h1;
    {
        float4 u0 = *reinterpret_cast<const float4*>(hbase + lg * 8);
        float4 u1 = *reinterpret_cast<const float4*>(hbase + lg * 8 + 4);
        float4 u2 = *reinterpret_cast<const float4*>(hbase + 32 + lg * 8);
        float4 u3 = *reinterpret_cast<const float4*>(hbase + 32 + lg * 8 + 4);
        h0[0] = f2bf(u0.x); h0[1] = f2bf(u0.y); h0[2] = f2bf(u0.z); h0[3] = f2bf(u0.w);
        h0[4] = f2bf(u1.x); h0[5] = f2bf(u1.y); h0[6] = f2bf(u1.z); h0[7] = f2bf(u1.w);
        h1[0] = f2bf(u2.x); h1[1] = f2bf(u2.y); h1[2] = f2bf(u2.z); h1[3] = f2bf(u2.w);
        h1[4] = f2bf(u3.x); h1[5] = f2bf(u3.y); h1[6] = f2bf(u3.z); h1[7] = f2bf(u3.w);
    }

    // ---- nb fragments for both tiles (k=64..127 of concat) ----
    const int er0 = wv * 16 + lr;                        // tile A (<100 always)
    const int er1 = mi1 * 16 + lr;
    const int ec1 = (er1 > NK - 1) ? NK - 1 : er1;       // clamp junk rows
    const float* arow0 = nbg + er0 * NHID + lg * 8;
    const float* arow1 = nbg + ec1 * NHID + lg * 8;
    short8 a0, a1, a2, a3;
    {
        float4 f0 = *reinterpret_cast<const float4*>(arow0);
        float4 f1 = *reinterpret_cast<const float4*>(arow0 + 4);
        float4 f2 = *reinterpret_cast<const float4*>(arow0 + 32);
        float4 f3 = *reinterpret_cast<const float4*>(arow0 + 36);
        a0[0] = f2bf(f0.x); a0[1] = f2bf(f0.y); a0[2] = f2bf(f0.z); a0[3] = f2bf(f0.w);
        a0[4] = f2bf(f1.x); a0[5] = f2bf(f1.y); a0[6] = f2bf(f1.z); a0[7] = f2bf(f1.w);
        a1[0] = f2bf(f2.x); a1[1] = f2bf(f2.y); a1[2] = f2bf(f2.z); a1[3] = f2bf(f2.w);
        a1[4] = f2bf(f3.x); a1[5] = f2bf(f3.y); a1[6] = f2bf(f3.z); a1[7] = f2bf(f3.w);
    }
    if (hasB) {
        float4 f0 = *reinterpret_cast<const float4*>(arow1);
        float4 f1 = *reinterpret_cast<const float4*>(arow1 + 4);
        float4 f2 = *reinterpret_cast<const float4*>(arow1 + 32);
        float4 f3 = *reinterpret_cast<const float4*>(arow1 + 36);
        a2[0] = f2bf(f0.x); a2[1] = f2bf(f0.y); a2[2] = f2bf(f0.z); a2[3] = f2bf(f0.w);
        a2[4] = f2bf(f1.x); a2[5] = f2bf(f1.y); a2[6] = f2bf(f1.z); a2[7] = f2bf(f1.w);
        a3[0] = f2bf(f2.x); a3[1] = f2bf(f2.y); a3[2] = f2bf(f2.z); a3[3] = f2bf(f2.w);
        a3[4] = f2bf(f3.x); a3[5] = f2bf(f3.y); a3[6] = f2bf(f3.z); a3[7] = f2bf(f3.w);
    }

    const short8* WaPv = reinterpret_cast<const short8*>(WaP);
    const short8* W1Pv = reinterpret_cast<const short8*>(W1P);
    const short8* W2Pv = reinterpret_cast<const short8*>(W2P);
    const float b3s = b3[0];
    const floatx4 b2v = *reinterpret_cast<const floatx4*>(b2 + lg * 4);
    const floatx4 w3v = *reinterpret_cast<const floatx4*>(W3 + lg * 4);

    // ---- stage lambdas (R22-proven math, split per layer) ----
    auto l1_stage = [&](char* zp, short8 b0, short8 b1) {
        #pragma unroll
        for (int t = 0; t < 6; ++t) {
            floatx4 acc = {0.f, 0.f, 0.f, 0.f};
            acc = __builtin_amdgcn_mfma_f32_16x16x32_bf16(WaPv[(t * 4 + 0) * 64 + ln], h0, acc, 0, 0, 0);
            acc = __builtin_amdgcn_mfma_f32_16x16x32_bf16(WaPv[(t * 4 + 1) * 64 + ln], h1, acc, 0, 0, 0);
            acc = __builtin_amdgcn_mfma_f32_16x16x32_bf16(WaPv[(t * 4 + 2) * 64 + ln], b0, acc, 0, 0, 0);
            acc = __builtin_amdgcn_mfma_f32_16x16x32_bf16(WaPv[(t * 4 + 3) * 64 + ln], b1, acc, 0, 0, 0);
            short4_t v;
            #pragma unroll
            for (int i = 0; i < 4; ++i) v[i] = f2bf(fmaxf(acc[i], 0.f));
            *reinterpret_cast<short4_t*>(zp + lr * ZSTRIDE + t * 32 + lg * 8) = v;
        }
    };
    auto l2_stage = [&](char* zp) {
        short8 za0 = *reinterpret_cast<const short8*>(zp + lr * ZSTRIDE +   0 + lg * 16);
        short8 za1 = *reinterpret_cast<const short8*>(zp + lr * ZSTRIDE +  64 + lg * 16);
        short8 za2 = *reinterpret_cast<const short8*>(zp + lr * ZSTRIDE + 128 + lg * 16);
        #pragma unroll
        for (int t = 0; t < 3; ++t) {
            floatx4 acc = {0.f, 0.f, 0.f, 0.f};
            acc = __builtin_amdgcn_mfma_f32_16x16x32_bf16(W1Pv[(t * 3 + 0) * 64 + ln], za0, acc, 0, 0, 0);
            acc = __builtin_amdgcn_mfma_f32_16x16x32_bf16(W1Pv[(t * 3 + 1) * 64 + ln], za1, acc, 0, 0, 0);
            acc = __builtin_amdgcn_mfma_f32_16x16x32_bf16(W1Pv[(t * 3 + 2) * 64 + ln], za2, acc, 0, 0, 0);
            floatx4 bb = *reinterpret_cast<const floatx4*>(b1v + t * 16 + lg * 4);
            short4_t v;
            #pragma unroll
            for (int i = 0; i < 4; ++i) v[i] = f2bf(fmaxf(acc[i] + bb[i], 0.f));
            *reinterpret_cast<short4_t*>(zp + lr * ZSTRIDE + t * 32 + lg * 8) = v;
        }
    };
    auto l3_stage = [&](char* zp, int mi) {
        short8 zb0 = *reinterpret_cast<const short8*>(zp + lr * ZSTRIDE + lg * 16);
        short8 zb1 = short8{0, 0, 0, 0, 0, 0, 0, 0};
        if (lg < 2)
            zb1 = *reinterpret_cast<const short8*>(zp + lr * ZSTRIDE + 64 + lg * 16);
        floatx4 c3 = {0.f, 0.f, 0.f, 0.f};
        c3 = __builtin_amdgcn_mfma_f32_16x16x32_bf16(W2Pv[ln], zb0, c3, 0, 0, 0);
        c3 = __builtin_amdgcn_mfma_f32_16x16x32_bf16(W2Pv[64 + ln], zb1, c3, 0, 0, 0);
        float p = 0.f;
        #pragma unroll
        for (int i = 0; i < 4; ++i)
            p += fmaxf(c3[i] + b2v[i], 0.f) * w3v[i];
        p += __shfl_xor(p, 16, 64);
        p += __shfl_xor(p, 32, 64);
        if (lg == 0 && mi * 16 + lr < NK) logit_s[mi * 16 + lr] = p + b3s;
    };

    // ---- interleaved schedule: A and B streams are independent ----
    l1_stage(zpA, a0, a1);
    if (hasB) l1_stage(zpB, a2, a3);
    l2_stage(zpA);
    if (hasB) l2_stage(zpB);
    l3_stage(zpA, wv);
    if (hasB) l3_stage(zpB, mi1);
    __syncthreads();                                  // the ONLY barrier

    // ---- softmax (redundant per wave, in-register; R18-proven) ----
    float l0 = logit_s[ln];
    float l1 = (ln < NK - 64) ? logit_s[64 + ln] : -1e30f;
    float m = fmaxf(l0, l1);
    #pragma unroll
    for (int off = 32; off > 0; off >>= 1) m = fmaxf(m, __shfl_xor(m, off, 64));
    float p0 = __expf(l0 - m);
    float p1 = (ln < NK - 64) ? __expf(l1 - m) : 0.f;
    float s = p0 + p1;
    #pragma unroll
    for (int off = 32; off > 0; off >>= 1) s += __shfl_xor(s, off, 64);
    float inv = 1.f / s;
    float w0 = p0 * inv;
    float w1 = p1 * inv;

    // ---- partial agg over this wave's 25 edges; contention-free store ----
    float a = 0.f;
    #pragma unroll
    for (int kk = 0; kk < 25; ++kk) {
        int k = wv * 25 + kk;
        float wk = __shfl((k < 64) ? w0 : w1, k & 63, 64);
        a += wk * nbg[k * NHID + ln];
    }
    part[((size_t)bl * 4 + wv) * NHID + ln] = a;
}

// ---- final head: reduce partials (256 thr, 4-way) -> heads -> Wf1 -> Wo ----
__global__ __launch_bounds__(256) void final_kernel(
    const int* __restrict__ user_ids,
    const float* __restrict__ user_table,
    const float* __restrict__ part,
    const float* __restrict__ Wh, const float* __restrict__ bh,
    const float* __restrict__ Wf1, const float* __restrict__ bf1,
    const float* __restrict__ Wo,  const float* __restrict__ bo,
    float* __restrict__ out)
{
    const int b = blockIdx.x, tid = threadIdx.x;
    const int q = tid >> 6, h = tid & 63;
    __shared__ float red[4][64];
    __shared__ float ue[64], agm[64], agh[64];

    // 4-way split of the 200-partial sum (50 per thread)
    {
        float sum = 0.f;
        const float* pb = part + ((size_t)b * NL * 4 + q) * NHID + h;
        #pragma unroll 5
        for (int i = 0; i < NL; ++i)
            sum += pb[(size_t)i * 4 * NHID];
        red[q][h] = sum;
    }
    if (q == 0) {
        const int uid = user_ids[b];
        ue[h] = user_table[(size_t)uid * 64 + h];
    }
    __syncthreads();
    if (q == 0)
        agm[h] = (red[0][h] + red[1][h] + red[2][h] + red[3][h]) * (1.f / 50.f);
    __syncthreads();
    if (q == 0) {
        const int n = h >> 4, d = h & 15;
        float hv = bh[h];
        #pragma unroll 4
        for (int i = 0; i < 64; ++i)
            hv += agm[i] * Wh[n * (64 * 16) + i * 16 + d];
        agh[h] = hv;
    }
    __syncthreads();
    if (q == 0) {
        float z = bf1[h];
        #pragma unroll 4
        for (int i = 0; i < 64; ++i) z += ue[i] * Wf1[i * 64 + h];
        #pragma unroll 4
        for (int i = 0; i < 64; ++i) z += agh[i] * Wf1[(64 + i) * 64 + h];
        float t = fmaxf(z, 0.f) * Wo[h];
        #pragma unroll
        for (int off = 32; off > 0; off >>= 1) t += __shfl_down(t, off, 64);
        if (h == 0) out[b] = 1.f / (1.f + __expf(-(t + bo[0])));
    }
}

extern "C" void kernel_launch(void* const* d_in, const int* in_sizes, int n_in,
                              void* d_out, int out_size, void* d_ws, size_t ws_size,
                              hipStream_t stream) {
    const int*   user_ids   = (const int*)d_in[0];
    const int*   history    = (const int*)d_in[2];
    const float* neighbor   = (const float*)d_in[3];
    const float* user_table = (const float*)d_in[4];
    const float* item_table = (const float*)d_in[5];
    const float* Wa  = (const float*)d_in[6];
    const float* W1  = (const float*)d_in[8];
    const float* b1  = (const float*)d_in[9];
    const float* W2  = (const float*)d_in[10];
    const float* b2  = (const float*)d_in[11];
    const float* W3  = (const float*)d_in[12];
    const float* b3  = (const float*)d_in[13];
    const float* Wh  = (const float*)d_in[14];
    const float* bh  = (const float*)d_in[15];
    const float* Wf1 = (const float*)d_in[16];
    const float* bf1 = (const float*)d_in[17];
    const float* Wo  = (const float*)d_in[18];
    const float* bo  = (const float*)d_in[19];

    char* ws = (char*)d_ws;
    short* WaP  = (short*)(ws);                              // 24576 B (full Wa)
    short* W1P  = (short*)(ws + 24576);                      // 9216 B
    short* W2P  = (short*)(ws + 33792);                      // 2048 B
    float* part = (float*)(ws + 36864);                      // NBL*4*64*4 = 13107200 B

    pack_kernel<<<64, 256, 0, stream>>>(Wa, W1, W2, WaP, W1P, W2P);
    edge_kernel<<<NBL, 256, 0, stream>>>(history, neighbor, item_table,
        b1, b2, W3, b3, WaP, W1P, W2P, part);
    final_kernel<<<NB, 256, 0, stream>>>(user_ids, user_table, part, Wh, bh,
                                         Wf1, bf1, Wo, bo, (float*)d_out);
}